// Round 3
// baseline (118.887 us; speedup 1.0000x reference)
//
#include <hip/hip_runtime.h>
#include <hip/hip_bf16.h>
#include <hip/hip_fp16.h>

typedef __attribute__((ext_vector_type(8))) short bf16x8;
typedef __attribute__((ext_vector_type(8))) unsigned short u16x8;
typedef __attribute__((ext_vector_type(4))) unsigned short u16x4;
typedef __attribute__((ext_vector_type(4))) float f32x4;

__device__ __forceinline__ unsigned short f2bf(float f) {
    __hip_bfloat16 h = __float2bfloat16(f);
    return *reinterpret_cast<unsigned short*>(&h);
}
__device__ __forceinline__ unsigned short f2h(float f) {
    __half h = __float2half(f);
    return *reinterpret_cast<unsigned short*>(&h);
}
__device__ __forceinline__ float h2f(unsigned short u) {
    __half h = *reinterpret_cast<__half*>(&u);
    return __half2float(h);
}

__device__ __forceinline__ void cp16(void* lds, const void* g) {
    __builtin_amdgcn_global_load_lds(
        (const __attribute__((address_space(1))) unsigned int*)g,
        (__attribute__((address_space(3))) unsigned int*)lds, 16, 0, 0);
}

// ---------------------------------------------------------------------------
// Kernel 1: pack W^T bf16: wt[(sel*128+n)*2048 + k] = w_sel[k*128 + n]
// ---------------------------------------------------------------------------
__global__ __launch_bounds__(256) void pack_w(
    const float* __restrict__ wq, const float* __restrict__ wk,
    const float* __restrict__ wv, unsigned short* __restrict__ wt)
{
    int idx = blockIdx.x * 256 + threadIdx.x;
    int n   = idx & 127;
    int k   = (idx >> 7) & 2047;
    int sel = idx >> 18;
    const float* w = (sel == 0) ? wq : (sel == 1) ? wk : wv;
    wt[(size_t)(sel * 128 + n) * 2048 + k] = f2bf(w[k * 128 + n]);
}

// ---------------------------------------------------------------------------
// Kernel 2a: K-split QKV GEMM. 768 blocks = 128 mtile x 3 ntile x 2 kc,
//   XCD-grouped (6 blocks of one mtile share x rows in one XCD's L2).
//   128x128 tile over K=1024 (32 steps). A reg-staged fp32->bf16; B via
//   global_load_lds. Output: fp16 partials Pp[kc][16384][384], no epilogue.
// ---------------------------------------------------------------------------
__global__ __launch_bounds__(256) void qkv_gemm_ks(
    const float* __restrict__ x, const unsigned short* __restrict__ wt,
    unsigned short* __restrict__ Pp)
{
    __shared__ __align__(16) unsigned short As[2][128 * 32];
    __shared__ __align__(16) unsigned short Bs[2][128 * 32];

    const int bid   = blockIdx.x;          // 768
    const int slot  = bid & 7;
    const int idx   = bid >> 3;            // 0..95
    const int mtile = slot + 8 * (idx / 6);
    const int sub   = idx % 6;
    const int ntile = sub >> 1;
    const int kc    = sub & 1;

    const int tid  = threadIdx.x;
    const int lane = tid & 63;
    const int w    = tid >> 6;
    const int wm   = w >> 1, wn = w & 1;
    const int grp  = lane >> 4, cl = lane & 15;

    const int arow0 = tid >> 2;            // 0..63
    const int ak8   = tid & 3;

    const float* xbase = x + (size_t)(mtile * 128) * 2048 + kc * 1024;
    const char*  wbyte = (const char*)(wt + (size_t)(ntile * 128) * 2048 + kc * 1024);

    float4 afl[2][2];

    auto gloadA = [&](int ks) {
        int k0 = ks * 32 + ak8 * 8;
        #pragma unroll
        for (int i = 0; i < 2; ++i) {
            const float* p = xbase + (size_t)(arow0 + i * 64) * 2048 + k0;
            afl[i][0] = *reinterpret_cast<const float4*>(p);
            afl[i][1] = *reinterpret_cast<const float4*>(p + 4);
        }
    };
    auto swriteA = [&](int buf) {
        #pragma unroll
        for (int i = 0; i < 2; ++i) {
            int row = arow0 + i * 64;
            u16x8 u;
            u[0] = f2bf(afl[i][0].x); u[1] = f2bf(afl[i][0].y);
            u[2] = f2bf(afl[i][0].z); u[3] = f2bf(afl[i][0].w);
            u[4] = f2bf(afl[i][1].x); u[5] = f2bf(afl[i][1].y);
            u[6] = f2bf(afl[i][1].z); u[7] = f2bf(afl[i][1].w);
            *reinterpret_cast<u16x8*>(&As[buf][row * 32 + ak8 * 8]) = u;
        }
    };
    auto stageB = [&](int buf, int ks) {
        #pragma unroll
        for (int i = 0; i < 2; ++i) {
            int   r0  = w * 32 + i * 16;
            char* dst = (char*)&Bs[buf][0] + r0 * 64;
            const char* src = wbyte + (size_t)(r0 + (lane >> 2)) * 4096
                              + ks * 64 + (lane & 3) * 16;
            cp16(dst, src);
        }
    };

    const f32x4 fz = {0.f, 0.f, 0.f, 0.f};
    f32x4 acc[4][4];
    #pragma unroll
    for (int mf = 0; mf < 4; ++mf)
        #pragma unroll
        for (int nf = 0; nf < 4; ++nf) acc[mf][nf] = fz;

    gloadA(0);
    stageB(0, 0);
    swriteA(0);
    __syncthreads();

    for (int ks = 0; ks < 32; ++ks) {
        int cur = ks & 1;
        if (ks < 31) { gloadA(ks + 1); stageB(cur ^ 1, ks + 1); }

        bf16x8 a[4], b[4];
        #pragma unroll
        for (int mf = 0; mf < 4; ++mf)
            a[mf] = *reinterpret_cast<const bf16x8*>(
                &As[cur][(wm * 64 + mf * 16 + cl) * 32 + grp * 8]);
        #pragma unroll
        for (int nf = 0; nf < 4; ++nf)
            b[nf] = *reinterpret_cast<const bf16x8*>(
                &Bs[cur][(wn * 64 + nf * 16 + cl) * 32 + grp * 8]);
        #pragma unroll
        for (int mf = 0; mf < 4; ++mf)
            #pragma unroll
            for (int nf = 0; nf < 4; ++nf)
                acc[mf][nf] = __builtin_amdgcn_mfma_f32_16x16x32_bf16(
                    a[mf], b[nf], acc[mf][nf], 0, 0, 0);

        if (ks < 31) swriteA(cur ^ 1);
        __syncthreads();
    }

    unsigned short* pp = Pp + (size_t)kc * 16384 * 384;
    #pragma unroll
    for (int mf = 0; mf < 4; ++mf) {
        int mrow = mtile * 128 + wm * 64 + mf * 16 + grp * 4;
        #pragma unroll
        for (int nf = 0; nf < 4; ++nf) {
            int ncol = ntile * 128 + wn * 64 + nf * 16 + cl;
            #pragma unroll
            for (int r = 0; r < 4; ++r)
                pp[(size_t)(mrow + r) * 384 + ncol] = f2h(acc[mf][nf][r]);
        }
    }
}

// ---------------------------------------------------------------------------
// Kernel 2b: merge Q/K partials + RoPE + bf16 pack (+K swizzle).
// ---------------------------------------------------------------------------
__global__ __launch_bounds__(256) void merge_qk(
    const unsigned short* __restrict__ Pp, const float* __restrict__ rc,
    const float* __restrict__ rs, unsigned short* __restrict__ Qb,
    unsigned short* __restrict__ Kb)
{
    int idx  = blockIdx.x * 256 + threadIdx.x;   // 524288
    int m    = idx >> 5;
    int col0 = (idx & 31) * 8;                   // 0..255
    const unsigned short* p0 = Pp + (size_t)m * 384 + col0;
    u16x8 a = *reinterpret_cast<const u16x8*>(p0);
    u16x8 b = *reinterpret_cast<const u16x8*>(p0 + (size_t)16384 * 384);
    float s[8];
    #pragma unroll
    for (int j = 0; j < 8; ++j) s[j] = h2f(a[j]) + h2f(b[j]);

    int t  = m & 2047;
    int h0 = col0 & 127;
    u16x8 ob;
    #pragma unroll
    for (int i = 0; i < 4; ++i) {
        float c  = rc[t * 128 + h0 + 2 * i];
        float sn = rs[t * 128 + h0 + 2 * i];
        ob[2 * i]     = f2bf(s[2 * i] * c - s[2 * i + 1] * sn);
        ob[2 * i + 1] = f2bf(s[2 * i + 1] * c + s[2 * i] * sn);
    }
    if (col0 < 128) {
        *reinterpret_cast<u16x8*>(Qb + (size_t)m * 128 + col0) = ob;
    } else {
        int bo = (col0 - 128) * 2;
        int bs = (bo & 128) | ((bo & 127) ^ ((m & 7) << 4));
        *reinterpret_cast<u16x8*>((char*)Kb + (size_t)m * 256 + bs) = ob;
    }
}

// ---------------------------------------------------------------------------
// Kernel 2c: merge V partials + transpose to VT (swizzled), via LDS tile.
//   Each block: 64 t-rows x 128 vh-cols.
// ---------------------------------------------------------------------------
__global__ __launch_bounds__(256) void merge_v(
    const unsigned short* __restrict__ Pp, unsigned short* __restrict__ VT)
{
    __shared__ unsigned short L[128 * 80];   // [vh][i], stride 80 (16B-aligned rows)

    const int tid = threadIdx.x;
    const int m0  = blockIdx.x * 64;         // 256 blocks

    {
        int i  = tid >> 2;                   // 0..63
        int c0 = (tid & 3) * 32;
        const unsigned short* p0 = Pp + (size_t)(m0 + i) * 384 + 256 + c0;
        #pragma unroll
        for (int cc = 0; cc < 4; ++cc) {
            u16x8 a = *reinterpret_cast<const u16x8*>(p0 + cc * 8);
            u16x8 b = *reinterpret_cast<const u16x8*>(p0 + cc * 8 + (size_t)16384 * 384);
            #pragma unroll
            for (int j = 0; j < 8; ++j)
                L[(c0 + cc * 8 + j) * 80 + i] = f2bf(h2f(a[j]) + h2f(b[j]));
        }
    }
    __syncthreads();
    {
        int vh  = tid >> 1;                  // 0..127
        int th0 = (tid & 1) * 32;
        int bb  = m0 >> 11;
        int tb  = m0 & 2047;
        char* vrow = (char*)VT + (size_t)(bb * 128 + vh) * 4096;
        #pragma unroll
        for (int cc = 0; cc < 4; ++cc) {
            int tl = th0 + cc * 8;
            u16x8 v = *reinterpret_cast<const u16x8*>(&L[vh * 80 + tl]);
            int bo = (tb + tl) * 2;
            int bs = (bo & ~127) | ((bo & 127) ^ ((vh & 7) << 4));
            *reinterpret_cast<u16x8*>(vrow + bs) = v;
        }
    }
}

// ---------------------------------------------------------------------------
// Kernel 2-mono (fallback, ws too small): round-2 monolithic GEMM + epilogue.
// ---------------------------------------------------------------------------
__global__ __launch_bounds__(256) void qkv_gemm_mono(
    const float* __restrict__ x, const unsigned short* __restrict__ wt,
    const float* __restrict__ rc, const float* __restrict__ rs,
    unsigned short* __restrict__ Qb, unsigned short* __restrict__ Kb,
    unsigned short* __restrict__ VT)
{
    __shared__ __align__(16) unsigned short As[2][128 * 32];
    __shared__ __align__(16) unsigned short Bs[2][128 * 32];

    const int bid   = blockIdx.x;
    const int slot  = bid & 7;
    const int idx   = bid >> 3;
    const int mtile = slot + 8 * (idx / 3);
    const int ntile = idx % 3;

    const int tid  = threadIdx.x;
    const int lane = tid & 63;
    const int wid  = tid >> 6;
    const int wm   = wid >> 1, wn = wid & 1;
    const int grp  = lane >> 4, cl = lane & 15;
    const int arow0 = tid >> 2;
    const int ak8   = tid & 3;

    const float*          xbase = x  + (size_t)(mtile * 128) * 2048;
    const unsigned short* wbase = wt + (size_t)(ntile * 128) * 2048;

    float4 afl[2][2];
    u16x8  bwl[2];

    auto gload = [&](int ks) {
        int k0 = ks * 32 + ak8 * 8;
        #pragma unroll
        for (int i = 0; i < 2; ++i) {
            int row = arow0 + i * 64;
            const float* p = xbase + (size_t)row * 2048 + k0;
            afl[i][0] = *reinterpret_cast<const float4*>(p);
            afl[i][1] = *reinterpret_cast<const float4*>(p + 4);
            bwl[i]    = *reinterpret_cast<const u16x8*>(wbase + (size_t)row * 2048 + k0);
        }
    };
    auto swrite = [&](int buf) {
        #pragma unroll
        for (int i = 0; i < 2; ++i) {
            int row = arow0 + i * 64;
            u16x8 u;
            u[0] = f2bf(afl[i][0].x); u[1] = f2bf(afl[i][0].y);
            u[2] = f2bf(afl[i][0].z); u[3] = f2bf(afl[i][0].w);
            u[4] = f2bf(afl[i][1].x); u[5] = f2bf(afl[i][1].y);
            u[6] = f2bf(afl[i][1].z); u[7] = f2bf(afl[i][1].w);
            *reinterpret_cast<u16x8*>(&As[buf][row * 32 + ak8 * 8]) = u;
            *reinterpret_cast<u16x8*>(&Bs[buf][row * 32 + ak8 * 8]) = bwl[i];
        }
    };

    const f32x4 fz = {0.f, 0.f, 0.f, 0.f};
    f32x4 acc[4][4];
    #pragma unroll
    for (int mf = 0; mf < 4; ++mf)
        #pragma unroll
        for (int nf = 0; nf < 4; ++nf) acc[mf][nf] = fz;

    gload(0); swrite(0); __syncthreads();

    for (int ks = 0; ks < 64; ++ks) {
        int cur = ks & 1;
        if (ks < 63) gload(ks + 1);
        bf16x8 a[4], b[4];
        #pragma unroll
        for (int mf = 0; mf < 4; ++mf)
            a[mf] = *reinterpret_cast<const bf16x8*>(
                &As[cur][(wm * 64 + mf * 16 + cl) * 32 + grp * 8]);
        #pragma unroll
        for (int nf = 0; nf < 4; ++nf)
            b[nf] = *reinterpret_cast<const bf16x8*>(
                &Bs[cur][(wn * 64 + nf * 16 + cl) * 32 + grp * 8]);
        #pragma unroll
        for (int mf = 0; mf < 4; ++mf)
            #pragma unroll
            for (int nf = 0; nf < 4; ++nf)
                acc[mf][nf] = __builtin_amdgcn_mfma_f32_16x16x32_bf16(
                    a[mf], b[nf], acc[mf][nf], 0, 0, 0);
        if (ks < 63) swrite(cur ^ 1);
        __syncthreads();
    }

    if (ntile == 0) {
        #pragma unroll
        for (int mf = 0; mf < 4; ++mf) {
            int mrow = mtile * 128 + wm * 64 + mf * 16 + grp * 4;
            #pragma unroll
            for (int nf = 0; nf < 4; ++nf) {
                int h = wn * 64 + nf * 16 + cl;
                #pragma unroll
                for (int r = 0; r < 4; ++r) {
                    int   m   = mrow + r;
                    int   t   = m & 2047;
                    float val = acc[mf][nf][r];
                    float pr  = __shfl_xor(val, 1, 64);
                    float cs  = rc[t * 128 + h];
                    float sn  = rs[t * 128 + h];
                    float res = (h & 1) ? fmaf(val, cs, pr * sn)
                                        : fmaf(val, cs, -pr * sn);
                    Qb[(size_t)m * 128 + h] = f2bf(res);
                }
            }
        }
    } else if (ntile == 1) {
        #pragma unroll
        for (int mf = 0; mf < 4; ++mf) {
            int mrow = mtile * 128 + wm * 64 + mf * 16 + grp * 4;
            #pragma unroll
            for (int nf = 0; nf < 4; ++nf) {
                int h = wn * 64 + nf * 16 + cl;
                #pragma unroll
                for (int r = 0; r < 4; ++r) {
                    int   m   = mrow + r;
                    int   t   = m & 2047;
                    float val = acc[mf][nf][r];
                    float pr  = __shfl_xor(val, 1, 64);
                    float cs  = rc[t * 128 + h];
                    float sn  = rs[t * 128 + h];
                    float res = (h & 1) ? fmaf(val, cs, pr * sn)
                                        : fmaf(val, cs, -pr * sn);
                    int bo = h * 2;
                    int bs = (bo & 128) | ((bo & 127) ^ ((m & 7) << 4));
                    Kb[(size_t)m * 128 + (bs >> 1)] = f2bf(res);
                }
            }
        }
    } else {
        #pragma unroll
        for (int mf = 0; mf < 4; ++mf) {
            int mrow = mtile * 128 + wm * 64 + mf * 16 + grp * 4;
            int bb   = mrow >> 11;
            int t0   = mrow & 2047;
            #pragma unroll
            for (int nf = 0; nf < 4; ++nf) {
                int h = wn * 64 + nf * 16 + cl;
                u16x4 pk;
                #pragma unroll
                for (int r = 0; r < 4; ++r) pk[r] = f2bf(acc[mf][nf][r]);
                int bo = (t0 * 2) & 127;
                int bs = ((t0 * 2) & ~127) | (bo ^ ((h & 7) << 4));
                *reinterpret_cast<u16x4*>(
                    &VT[(size_t)(bb * 128 + h) * 2048 + (bs >> 1)]) = pk;
            }
        }
    }
}

// ---------------------------------------------------------------------------
// Kernel 3: causal flash attention (unchanged from round 2).
// ---------------------------------------------------------------------------
__global__ __launch_bounds__(256, 2) void flash_attn(
    const unsigned short* __restrict__ Qb, const unsigned short* __restrict__ Kb,
    const unsigned short* __restrict__ VT, float* __restrict__ Op,
    float2* __restrict__ ML, float* __restrict__ out, int nchunk)
{
    __shared__ __align__(16) unsigned short Ks[2][64 * 128];
    __shared__ __align__(16) unsigned short Vs[2][128 * 64];
    __shared__ __align__(16) unsigned short Ps[4][16 * 72];

    const int g      = blockIdx.x;
    const int per_mt = 8 * nchunk;
    const int mtd    = g / per_mt;
    const int mt     = 31 - mtd;
    const int rem    = g - mtd * per_mt;
    const int c      = rem >> 3;
    const int b      = rem & 7;

    const int tid  = threadIdx.x;
    const int lane = tid & 63;
    const int w    = tid >> 6;
    const int grp  = lane >> 4, cl = lane & 15;

    const int NT   = mt + 1;
    const int T0   = (NT + 1) >> 1;
    const int tbeg = (nchunk == 2 && c == 1) ? T0 : 0;
    const int tend = (nchunk == 2 && c == 0) ? T0 : NT;

    const int   q0    = mt * 64 + w * 16;
    const float scale = 0.08838834764831845f;

    bf16x8 aq[4];
    {
        const unsigned short* qp = Qb + (size_t)(b * 2048 + q0 + cl) * 128 + grp * 8;
        #pragma unroll
        for (int kc = 0; kc < 4; ++kc)
            aq[kc] = *reinterpret_cast<const bf16x8*>(qp + kc * 32);
    }

    const f32x4 fz = {0.f, 0.f, 0.f, 0.f};
    f32x4 o[8];
    #pragma unroll
    for (int nf = 0; nf < 8; ++nf) o[nf] = fz;
    float mrun[4], lrun[4];
    #pragma unroll
    for (int r = 0; r < 4; ++r) { mrun[r] = -INFINITY; lrun[r] = 0.f; }

    const char* kgb = (const char*)(Kb + (size_t)b * 2048 * 128);
    const char* vgb = (const char*)(VT + (size_t)b * 128 * 2048);

    auto stage = [&](int d, int t) {
        const char* ks = kgb + (size_t)t * 64 * 256;
        char* kd = (char*)&Ks[d][0];
        #pragma unroll
        for (int i = 0; i < 4; ++i) {
            int off = w * 4096 + i * 1024 + lane * 16;
            cp16(kd + off, ks + off);
        }
        const char* vsb = vgb + (size_t)t * 128;
        char* vd = (char*)&Vs[d][0];
        #pragma unroll
        for (int i = 0; i < 4; ++i) {
            int off = w * 4096 + i * 1024 + lane * 16;
            cp16(vd + off, vsb + (size_t)(off >> 7) * 4096 + (off & 127));
        }
    };

    if (tbeg < tend) stage(0, tbeg);
    __syncthreads();

    int cur = 0;
    for (int t = tbeg; t < tend; ++t) {
        if (t + 1 < tend) stage(cur ^ 1, t + 1);

        const char* kb   = (const char*)&Ks[cur][0];
        const char* vb   = (const char*)&Vs[cur][0];
        const bool  diag = (t == mt);
        const int   jmax = diag ? (w + 1) : 4;

        float p[4][4];
        float mx[4];
        #pragma unroll
        for (int r = 0; r < 4; ++r) mx[r] = -INFINITY;

        #pragma unroll
        for (int j = 0; j < 4; ++j) {
            #pragma unroll
            for (int r = 0; r < 4; ++r) p[j][r] = 0.f;
            if (j < jmax) {
                int   row = j * 16 + cl;
                f32x4 s   = fz;
                #pragma unroll
                for (int kc = 0; kc < 4; ++kc) {
                    int bo = kc * 64 + grp * 16;
                    int bs = (bo & 128) | ((bo & 127) ^ ((row & 7) << 4));
                    bf16x8 kf = *reinterpret_cast<const bf16x8*>(kb + row * 256 + bs);
                    s = __builtin_amdgcn_mfma_f32_16x16x32_bf16(aq[kc], kf, s, 0, 0, 0);
                }
                #pragma unroll
                for (int r = 0; r < 4; ++r) {
                    float a = s[r] * scale;
                    if (diag && j == w && cl > grp * 4 + r) a = -INFINITY;
                    p[j][r] = a;
                    mx[r]   = fmaxf(mx[r], a);
                }
            }
        }
        #pragma unroll
        for (int d = 1; d < 16; d <<= 1)
            #pragma unroll
            for (int r = 0; r < 4; ++r)
                mx[r] = fmaxf(mx[r], __shfl_xor(mx[r], d, 64));

        float alpha[4], psum[4];
        #pragma unroll
        for (int r = 0; r < 4; ++r) {
            float mn = fmaxf(mrun[r], mx[r]);
            alpha[r] = __expf(mrun[r] - mn);
            mrun[r]  = mn;
            psum[r]  = 0.f;
        }
        #pragma unroll
        for (int j = 0; j < 4; ++j)
            if (j < jmax)
                #pragma unroll
                for (int r = 0; r < 4; ++r) {
                    p[j][r] = __expf(p[j][r] - mrun[r]);
                    psum[r] += p[j][r];
                }
        #pragma unroll
        for (int d = 1; d < 16; d <<= 1)
            #pragma unroll
            for (int r = 0; r < 4; ++r)
                psum[r] += __shfl_xor(psum[r], d, 64);
        #pragma unroll
        for (int r = 0; r < 4; ++r)
            lrun[r] = lrun[r] * alpha[r] + psum[r];
        #pragma unroll
        for (int nf = 0; nf < 8; ++nf)
            #pragma unroll
            for (int r = 0; r < 4; ++r) o[nf][r] *= alpha[r];

        char* pwb = (char*)&Ps[w][0];
        #pragma unroll
        for (int j = 0; j < 4; ++j)
            #pragma unroll
            for (int r = 0; r < 4; ++r) {
                int prow = grp * 4 + r;
                int bytec = ((j * 16 + cl) * 2) ^ ((prow & 7) << 4);
                *reinterpret_cast<unsigned short*>(pwb + prow * 144 + bytec) =
                    f2bf(p[j][r]);
            }

        const char* pb = (const char*)&Ps[w][0];
        #pragma unroll
        for (int half = 0; half < 2; ++half) {
            int pbo = half * 64 + grp * 16;
            bf16x8 pa = *reinterpret_cast<const bf16x8*>(
                pb + cl * 144 + (pbo ^ ((cl & 7) << 4)));
            #pragma unroll
            for (int nf = 0; nf < 8; ++nf) {
                int h  = nf * 16 + cl;
                int bs = (half * 64 + grp * 16) ^ ((h & 7) << 4);
                bf16x8 vf = *reinterpret_cast<const bf16x8*>(vb + h * 128 + bs);
                o[nf] = __builtin_amdgcn_mfma_f32_16x16x32_bf16(pa, vf, o[nf], 0, 0, 0);
            }
        }
        __syncthreads();
        cur ^= 1;
    }

    if (nchunk == 2) {
        #pragma unroll
        for (int nf = 0; nf < 8; ++nf)
            #pragma unroll
            for (int r = 0; r < 4; ++r) {
                size_t rowg = (size_t)c * 16384 + b * 2048 + q0 + grp * 4 + r;
                Op[rowg * 128 + nf * 16 + cl] = o[nf][r];
            }
        if (cl == 0)
            #pragma unroll
            for (int r = 0; r < 4; ++r)
                ML[(size_t)c * 16384 + b * 2048 + q0 + grp * 4 + r] =
                    make_float2(mrun[r], lrun[r]);
    } else {
        float inv[4];
        #pragma unroll
        for (int r = 0; r < 4; ++r) inv[r] = 1.0f / lrun[r];
        #pragma unroll
        for (int nf = 0; nf < 8; ++nf)
            #pragma unroll
            for (int r = 0; r < 4; ++r)
                out[(size_t)(b * 2048 + q0 + grp * 4 + r) * 128 + nf * 16 + cl] =
                    o[nf][r] * inv[r];
    }
}

// ---------------------------------------------------------------------------
// Kernel 4: merge the 2 KV-chunk partials.
// ---------------------------------------------------------------------------
__global__ __launch_bounds__(256) void merge2(
    const float* __restrict__ Op, const float2* __restrict__ ML,
    float* __restrict__ out)
{
    int idx = blockIdx.x * 256 + threadIdx.x;
    int row = idx >> 5, hq = idx & 31;
    float2 ml0 = ML[row];
    float2 ml1 = ML[16384 + row];
    float  m  = fmaxf(ml0.x, ml1.x);
    float  e0 = __expf(ml0.x - m);
    float  e1 = __expf(ml1.x - m);
    float  inv = 1.0f / (ml0.y * e0 + ml1.y * e1);
    f32x4 o0 = *reinterpret_cast<const f32x4*>(Op + (size_t)row * 128 + hq * 4);
    f32x4 o1 = *reinterpret_cast<const f32x4*>(Op + ((size_t)16384 + row) * 128 + hq * 4);
    f32x4 res;
    #pragma unroll
    for (int i = 0; i < 4; ++i) res[i] = (o0[i] * e0 + o1[i] * e1) * inv;
    *reinterpret_cast<f32x4*>(out + (size_t)row * 128 + hq * 4) = res;
}

// ---------------------------------------------------------------------------
extern "C" void kernel_launch(void* const* d_in, const int* in_sizes, int n_in,
                              void* d_out, int out_size, void* d_ws, size_t ws_size,
                              hipStream_t stream)
{
    const float* x  = (const float*)d_in[0];
    const float* wq = (const float*)d_in[1];
    const float* wk = (const float*)d_in[2];
    const float* wv = (const float*)d_in[3];
    const float* rc = (const float*)d_in[4];
    const float* rs = (const float*)d_in[5];
    float* out = (float*)d_out;

    char* ws = (char*)d_ws;
    const size_t MB = 1u << 20;
    unsigned short* wt = (unsigned short*)(ws);                  // 1.5 MB
    unsigned short* Qb = (unsigned short*)(ws + 2 * MB);         // 4 MB
    unsigned short* Kb = (unsigned short*)(ws + 6 * MB);         // 4 MB
    unsigned short* VT = (unsigned short*)(ws + 10 * MB);        // 4 MB

    pack_w<<<3072, 256, 0, stream>>>(wq, wk, wv, wt);

    if (ws_size >= 39 * MB) {
        // Full path: K-split GEMM -> fp16 partials Pp (24 MiB @14MB),
        // then merges; flash's Op/ML time-share the Pp region.
        unsigned short* Pp = (unsigned short*)(ws + 14 * MB);    // 24 MiB
        float*          Op = (float*)        (ws + 14 * MB);     // 16 MiB (after Pp dead)
        float2*         ML = (float2*)       (ws + 30 * MB);     // 256 KB

        qkv_gemm_ks<<<768,  256, 0, stream>>>(x, wt, Pp);
        merge_qk   <<<2048, 256, 0, stream>>>(Pp, rc, rs, Qb, Kb);
        merge_v    <<<256,  256, 0, stream>>>(Pp, VT);
        flash_attn <<<512,  256, 0, stream>>>(Qb, Kb, VT, Op, ML, out, 2);
        merge2     <<<2048, 256, 0, stream>>>(Op, ML, out);
    } else {
        // Fallback (small ws): round-2 monolithic path.
        float*  Op = (float*) (ws + 14 * MB);
        float2* ML = (float2*)(ws + 30 * MB);
        const int nchunk = (ws_size >= (size_t)31 * MB) ? 2 : 1;
        qkv_gemm_mono<<<384, 256, 0, stream>>>(x, wt, rc, rs, Qb, Kb, VT);
        flash_attn<<<32 * 8 * nchunk, 256, 0, stream>>>(Qb, Kb, VT, Op, ML, out, nchunk);
        if (nchunk == 2)
            merge2<<<2048, 256, 0, stream>>>(Op, ML, out);
    }
}